// Round 1
// baseline (12174.832 us; speedup 1.0000x reference)
//
#include <hip/hip_runtime.h>
#include <hip/hip_bf16.h>
#include <math.h>

// Problem constants (match reference)
#define NL    8
#define D_    1024
#define RANK_ 64
#define SMAX_ 512
#define VOC_  32000
#define B_    4
#define S_    512
#define T_    (B_*S_)   // 2048 tokens
#define H_    (4*D_)    // 4096

// ---------------------------------------------------------------------------
// Embedding gather: x[t,:] = emb[ids[t],:]
// ---------------------------------------------------------------------------
__global__ __launch_bounds__(256) void embed_kernel(const int* __restrict__ ids,
                                                    const float* __restrict__ emb,
                                                    float* __restrict__ x) {
    int t = blockIdx.x;
    int id = ids[t];
    const float4* src = (const float4*)(emb + (size_t)id * D_);
    float4* dst = (float4*)(x + (size_t)t * D_);
    dst[threadIdx.x] = src[threadIdx.x];   // 256 threads x float4 = 1024 floats
}

// ---------------------------------------------------------------------------
// LayerNorm: one block (256 thr) per row of D=1024. eps=1e-5, affine.
// ---------------------------------------------------------------------------
__global__ __launch_bounds__(256) void ln_kernel(const float* __restrict__ in,
                                                 const float* __restrict__ w,
                                                 const float* __restrict__ b,
                                                 float* __restrict__ out) {
    int t = blockIdx.x;
    int tid = threadIdx.x;
    int wave = tid >> 6, lane = tid & 63;
    __shared__ float red[8];

    float4 v4 = ((const float4*)(in + (size_t)t * D_))[tid];
    float s = v4.x + v4.y + v4.z + v4.w;
    #pragma unroll
    for (int off = 32; off; off >>= 1) s += __shfl_xor(s, off);
    if (lane == 0) red[wave] = s;
    __syncthreads();
    float mean = (red[0] + red[1] + red[2] + red[3]) * (1.0f / D_);

    float dx = v4.x - mean, dy = v4.y - mean, dz = v4.z - mean, dw = v4.w - mean;
    float ss = dx*dx + dy*dy + dz*dz + dw*dw;
    #pragma unroll
    for (int off = 32; off; off >>= 1) ss += __shfl_xor(ss, off);
    if (lane == 0) red[4 + wave] = ss;
    __syncthreads();
    float var = (red[4] + red[5] + red[6] + red[7]) * (1.0f / D_);
    float rstd = rsqrtf(var + 1e-5f);

    float4 wv = ((const float4*)w)[tid];
    float4 bv = ((const float4*)b)[tid];
    float4 o;
    o.x = dx * rstd * wv.x + bv.x;
    o.y = dy * rstd * wv.y + bv.y;
    o.z = dz * rstd * wv.z + bv.z;
    o.w = dw * rstd * wv.w + bv.w;
    ((float4*)(out + (size_t)t * D_))[tid] = o;
}

// ---------------------------------------------------------------------------
// Mixing matrix: M[t,s] = (s<=t) ? dot(P[t,:64], Q[s,:64]) : 0
// block (16,16) computes a 16x16 tile. LDS padded to 65 to avoid bank conflicts.
// ---------------------------------------------------------------------------
__global__ __launch_bounds__(256) void mix_kernel(const float* __restrict__ P,
                                                  const float* __restrict__ Q,
                                                  float* __restrict__ Mout) {
    __shared__ float Ps[16][65];
    __shared__ float Qs[16][65];
    int s0 = blockIdx.x * 16, t0 = blockIdx.y * 16;
    int tid = threadIdx.y * 16 + threadIdx.x;
    int r = tid >> 4, c4 = (tid & 15) * 4;

    float4 pv = *(const float4*)(P + (size_t)(t0 + r) * RANK_ + c4);
    float4 qv = *(const float4*)(Q + (size_t)(s0 + r) * RANK_ + c4);
    Ps[r][c4+0] = pv.x; Ps[r][c4+1] = pv.y; Ps[r][c4+2] = pv.z; Ps[r][c4+3] = pv.w;
    Qs[r][c4+0] = qv.x; Qs[r][c4+1] = qv.y; Qs[r][c4+2] = qv.z; Qs[r][c4+3] = qv.w;
    __syncthreads();

    int t = t0 + threadIdx.y, s = s0 + threadIdx.x;
    float acc = 0.0f;
    if (s <= t) {
        #pragma unroll
        for (int k = 0; k < RANK_; ++k)
            acc += Ps[threadIdx.y][k] * Qs[threadIdx.x][k];
    }
    Mout[(size_t)t * S_ + s] = acc;
}

// ---------------------------------------------------------------------------
// GELU (tanh approximation, matches jax.nn.gelu default approximate=True)
// ---------------------------------------------------------------------------
__device__ __forceinline__ float gelu_f(float x) {
    float x3 = x * x * x;
    return 0.5f * x * (1.0f + tanhf(0.7978845608028654f * (x + 0.044715f * x3)));
}

// ---------------------------------------------------------------------------
// SGEMM: C = A(MxK) @ B(KxN) [+bias] [gelu] [+resid]; optional batching via
// blockIdx.z with strides. 128x128 tile, BK=8, 256 threads, 8x8 micro-tile
// split as 4x(4x4) halves so LDS fragment reads are <=2-way bank aliased.
// All dims must be divisible by 128 (M,N) and 8 (K) - true for every call here.
// FLAGS: bit0=bias, bit1=gelu, bit2=residual
// ---------------------------------------------------------------------------
template<int FLAGS>
__global__ __launch_bounds__(256) void sgemm(const float* __restrict__ A,
                                             const float* __restrict__ Bm,
                                             const float* __restrict__ bias,
                                             const float* __restrict__ Rs,
                                             float* __restrict__ C,
                                             int Mdim, int Ndim, int Kdim,
                                             long sA, long sB, long sC) {
    constexpr bool F_BIAS  = (FLAGS & 1) != 0;
    constexpr bool F_GELU  = (FLAGS & 2) != 0;
    constexpr bool F_RESID = (FLAGS & 4) != 0;

    A  += (size_t)blockIdx.z * sA;
    Bm += (size_t)blockIdx.z * sB;
    C  += (size_t)blockIdx.z * sC;
    if (F_RESID) Rs += (size_t)blockIdx.z * sC;

    __shared__ float As[8][128];
    __shared__ float Bs[8][128];

    int tid = threadIdx.x;
    int tx = tid & 15, ty = tid >> 4;
    int bn0 = blockIdx.x * 128, bm0 = blockIdx.y * 128;

    // global-load assignments
    int arow = tid >> 1;            // 0..127
    int acol = (tid & 1) * 4;       // 0 or 4
    int brow = tid >> 5;            // 0..7
    int bcol = (tid & 31) * 4;      // 0..124

    const float* Aptr = A + (size_t)(bm0 + arow) * Kdim + acol;
    const float* Bptr = Bm + (size_t)brow * Ndim + bn0 + bcol;

    float acc[8][8];
    #pragma unroll
    for (int i = 0; i < 8; ++i)
        #pragma unroll
        for (int j = 0; j < 8; ++j) acc[i][j] = 0.0f;

    for (int k0 = 0; k0 < Kdim; k0 += 8) {
        float4 av = *(const float4*)Aptr;
        float4 bv = *(const float4*)Bptr;
        __syncthreads();
        As[acol + 0][arow] = av.x;
        As[acol + 1][arow] = av.y;
        As[acol + 2][arow] = av.z;
        As[acol + 3][arow] = av.w;
        *(float4*)&Bs[brow][bcol] = bv;
        __syncthreads();

        #pragma unroll
        for (int k = 0; k < 8; ++k) {
            float ra[8], rb[8];
            *(float4*)&ra[0] = *(const float4*)&As[k][ty * 4];
            *(float4*)&ra[4] = *(const float4*)&As[k][64 + ty * 4];
            *(float4*)&rb[0] = *(const float4*)&Bs[k][tx * 4];
            *(float4*)&rb[4] = *(const float4*)&Bs[k][64 + tx * 4];
            #pragma unroll
            for (int i = 0; i < 8; ++i)
                #pragma unroll
                for (int j = 0; j < 8; ++j)
                    acc[i][j] += ra[i] * rb[j];
        }
        Aptr += 8;
        Bptr += (size_t)8 * Ndim;
    }

    // epilogue
    #pragma unroll
    for (int hi = 0; hi < 2; ++hi) {
        #pragma unroll
        for (int i = 0; i < 4; ++i) {
            int r = bm0 + hi * 64 + ty * 4 + i;
            #pragma unroll
            for (int hj = 0; hj < 2; ++hj) {
                int c = bn0 + hj * 64 + tx * 4;
                float o[4];
                #pragma unroll
                for (int j = 0; j < 4; ++j) {
                    float val = acc[hi * 4 + i][hj * 4 + j];
                    if (F_BIAS) val += bias[c + j];
                    if (F_GELU) val = gelu_f(val);
                    o[j] = val;
                }
                if (F_RESID) {
                    float4 rv = *(const float4*)&Rs[(size_t)r * Ndim + c];
                    o[0] += rv.x; o[1] += rv.y; o[2] += rv.z; o[3] += rv.w;
                }
                *(float4*)&C[(size_t)r * Ndim + c] = make_float4(o[0], o[1], o[2], o[3]);
            }
        }
    }
}

// ---------------------------------------------------------------------------
extern "C" void kernel_launch(void* const* d_in, const int* in_sizes, int n_in,
                              void* d_out, int out_size, void* d_ws, size_t ws_size,
                              hipStream_t stream) {
    const int*   ids   = (const int*)  d_in[0];
    const float* emb   = (const float*)d_in[1];
    const float* Wv    = (const float*)d_in[2];
    const float* Wo    = (const float*)d_in[3];
    const float* P     = (const float*)d_in[4];
    const float* Q     = (const float*)d_in[5];
    const float* ln1w  = (const float*)d_in[6];
    const float* ln1b  = (const float*)d_in[7];
    const float* ln2w  = (const float*)d_in[8];
    const float* ln2b  = (const float*)d_in[9];
    const float* w1    = (const float*)d_in[10];
    const float* b1    = (const float*)d_in[11];
    const float* w2    = (const float*)d_in[12];
    const float* b2    = (const float*)d_in[13];
    const float* lnfw  = (const float*)d_in[14];
    const float* lnfb  = (const float*)d_in[15];
    const float* headw = (const float*)d_in[16];
    const float* headb = (const float*)d_in[17];
    float* out = (float*)d_out;

    float* ws   = (float*)d_ws;
    float* x    = ws;                        // T*D
    float* h    = x    + (size_t)T_ * D_;    // T*D
    float* v    = h    + (size_t)T_ * D_;    // T*D
    float* attn = v    + (size_t)T_ * D_;    // T*D
    float* Mbuf = attn + (size_t)T_ * D_;    // S*S
    float* mid  = Mbuf + (size_t)S_ * S_;    // T*H

    embed_kernel<<<T_, 256, 0, stream>>>(ids, emb, x);

    for (int l = 0; l < NL; ++l) {
        const float* Wvl = Wv + (size_t)l * D_ * D_;
        const float* Wol = Wo + (size_t)l * D_ * D_;
        const float* Pl  = P  + (size_t)l * SMAX_ * RANK_;
        const float* Ql  = Q  + (size_t)l * SMAX_ * RANK_;
        const float* w1l = w1 + (size_t)l * D_ * H_;
        const float* b1l = b1 + (size_t)l * H_;
        const float* w2l = w2 + (size_t)l * H_ * D_;
        const float* b2l = b2 + (size_t)l * D_;

        // h = LN1(x)
        ln_kernel<<<T_, 256, 0, stream>>>(x, ln1w + l * D_, ln1b + l * D_, h);
        // v = h @ Wv
        sgemm<0><<<dim3(D_/128, T_/128, 1), 256, 0, stream>>>(
            h, Wvl, nullptr, nullptr, v, T_, D_, D_, 0, 0, 0);
        // M = (P @ Q^T) * tril
        mix_kernel<<<dim3(S_/16, S_/16), dim3(16,16), 0, stream>>>(Pl, Ql, Mbuf);
        // attn[b] = M @ v[b]  (batched over B)
        sgemm<0><<<dim3(D_/128, S_/128, B_), 256, 0, stream>>>(
            Mbuf, v, nullptr, nullptr, attn, S_, D_, S_,
            0, (long)S_ * D_, (long)S_ * D_);
        // x = x + attn @ Wo
        sgemm<4><<<dim3(D_/128, T_/128, 1), 256, 0, stream>>>(
            attn, Wol, nullptr, x, x, T_, D_, D_, 0, 0, 0);
        // h = LN2(x)
        ln_kernel<<<T_, 256, 0, stream>>>(x, ln2w + l * D_, ln2b + l * D_, h);
        // mid = gelu(h @ w1 + b1)
        sgemm<3><<<dim3(H_/128, T_/128, 1), 256, 0, stream>>>(
            h, w1l, b1l, nullptr, mid, T_, H_, D_, 0, 0, 0);
        // x = x + mid @ w2 + b2
        sgemm<5><<<dim3(D_/128, T_/128, 1), 256, 0, stream>>>(
            mid, w2l, b2l, x, x, T_, D_, H_, 0, 0, 0);
    }

    // final LN + head
    ln_kernel<<<T_, 256, 0, stream>>>(x, lnfw, lnfb, h);
    sgemm<1><<<dim3(VOC_/128, T_/128, 1), 256, 0, stream>>>(
        h, headw, headb, nullptr, out, T_, VOC_, D_, 0, 0, 0);
}